// Round 11
// baseline (1458.870 us; speedup 1.0000x reference)
//
#include <hip/hip_runtime.h>
#include <stdint.h>

typedef __bf16 bf16x8 __attribute__((ext_vector_type(8)));
typedef float  floatx4 __attribute__((ext_vector_type(4)));
typedef int    i32x4  __attribute__((ext_vector_type(4)));

#define T_LEN 512
#define NG    (T_LEN / 4)   // 128 time-groups of 4 steps
#define BT    4             // batch rows per block-pair
#define XS    72            // x group-tile row stride (bf16)
#define HIS   144           // h int8 LDS row stride (bytes)
#define HFS   132           // final h1 fp32 row stride

#define GB_GROUP 2048                       // one h0 group tile: 16 rows x 128 B
#define WS_FLAGS ((size_t)128 * NG * 4)     // u32 flag per (pair, group) = 64 KiB
#define WS_DATA  ((size_t)128 * NG * GB_GROUP)  // 32 MiB
#define WS_NEEDED (WS_FLAGS + WS_DATA)

#if __has_builtin(__builtin_amdgcn_exp2f)
#define EXP2(x) __builtin_amdgcn_exp2f(x)
#else
#define EXP2(x) exp2f(x)
#endif

#define MFMA_BF(a,b,c)  __builtin_amdgcn_mfma_f32_16x16x32_bf16((a),(b),(c),0,0,0)
#define MFMA_I8(a,b,c)  __builtin_amdgcn_mfma_i32_16x16x64_i8((a),(b),(c),0,0,0)

// Raw workgroup barrier: drains LDS ops only (lgkmcnt), NOT vmcnt.
#define BARRIER_LDS() asm volatile("s_waitcnt lgkmcnt(0)\n\ts_barrier" ::: "memory")

// quantization: h -> q*1/127 ; w -> q*1/254 (|w| clamped at 0.5)
#define L2E   1.4426950408889634f
#define S_RZ  (-L2E / (254.f * 127.f))        // i32 -> -log2e * preact
#define S_N   (-2.f * L2E / (254.f * 127.f))  // i32 -> -2*log2e * preact

__device__ __forceinline__ float rcpf(float x) { return __builtin_amdgcn_rcpf(x); }

__device__ __forceinline__ bf16x8 wfrag_bf(const float* W, int ldk, int row, int k0, float scale) {
    const float* p = W + (size_t)row * ldk + k0;
    bf16x8 r;
    #pragma unroll
    for (int j = 0; j < 8; ++j) r[j] = (__bf16)(p[j] * scale);
    return r;
}
__device__ __forceinline__ i32x4 wfrag_i8(const float* W, int ldk, int row, int k0) {
    const float* p = W + (size_t)row * ldk + k0;
    i32x4 r;
    #pragma unroll
    for (int d = 0; d < 4; ++d) {
        uint32_t dw = 0;
        #pragma unroll
        for (int j = 0; j < 4; ++j) {
            float q = __builtin_rintf(p[d * 4 + j] * 254.f);
            q = fminf(127.f, fmaxf(-127.f, q));
            dw |= ((uint32_t)((int)q & 0xff)) << (8 * j);
        }
        r[d] = (int)dw;
    }
    return r;
}

// ===========================================================================
// SPLIT kernel: 256 blocks x 512 threads (8 waves) — L0 and L1 of one batch
// pair run on SEPARATE CUs (all 256 CUs busy vs 128 before). Per-SIMD issue
// per interval halves (MFMA ~612->~306 cy, gate VALU ~520->~260 cy).
// Cross-layer h0 flows producer->consumer through a global stream:
//   producer: per step, byte-write its h0 row-tile into gdata[pair][G];
//             at group end: vmcnt(0) drain -> barrier -> tid0 release-flag
//             (agent scope => buffer_wbl2: lines reach the coherent point).
//   consumer: acquire-poll flag[G-2] (buffer_inv) and preload the 2 KB tile
//             into 16 regs, 4 intervals before use (lag 12 steps total).
// ALL 128 groups are buffered -> producer never waits -> deadlock-free even
// without co-residency. Per-step math identical to the monolithic kernel ->
// bit-identical output. Pairing (bid, bid+8) keeps a pair on one XCD (%8 map).
// ===========================================================================
__global__ __launch_bounds__(512, 2) void gru_split(
    const float* __restrict__ x,
    const float* __restrict__ Wih0, const float* __restrict__ Whh0,
    const float* __restrict__ bih0, const float* __restrict__ bhh0,
    const float* __restrict__ Wih1, const float* __restrict__ Whh1,
    const float* __restrict__ bih1, const float* __restrict__ bhh1,
    const float* __restrict__ Wfc,  const float* __restrict__ bfc,
    float* __restrict__ out,
    unsigned* __restrict__ flags, signed char* __restrict__ gdata)
{
    __shared__ __align__(16) __bf16      xg[2][16 * XS];    // producer only
    __shared__ __align__(16) signed char h0b[2][16 * HIS];  // producer only
    __shared__ __align__(16) signed char h1b[2][16 * HIS];  // consumer only
    __shared__ __align__(16) float       hfin[16 * HFS];    // consumer only

    const int tid  = threadIdx.x;
    const int lane = tid & 63;
    const int ln16 = lane & 15;
    const int quad = lane >> 4;
    const int q8   = quad * 8;
    const int q16  = quad * 16;
    const int wave = tid >> 6;        // 0..7
    const int bid  = blockIdx.x;
    const int role = (bid >> 3) & 1;                    // 0 = L0, 1 = L1
    const int pairid = ((bid >> 4) << 3) | (bid & 7);   // 0..127, pair on same XCD
    const int brow = pairid * BT;
    signed char* gb = gdata + (size_t)pairid * NG * GB_GROUP;
    unsigned*    fl = flags + (size_t)pairid * NG;

    for (int i = tid; i < 16 * HIS; i += 512) {
        h0b[0][i] = 0; h0b[1][i] = 0;
        h1b[0][i] = 0; h1b[1][i] = 0;
    }
    for (int i = tid; i < 16 * XS; i += 512) {
        xg[0][i] = (__bf16)0.f; xg[1][i] = (__bf16)0.f;
    }
    __syncthreads();                  // init barrier

    if (role == 0) {
        // ===== producer: layer-0, cols [16w,16w+16) =====
        const int c = wave * 16 + ln16;
        const float bNi = -2.f * L2E * bih0[256 + c];
        const float bNh = -2.f * L2E * bhh0[256 + c];
        const float bR  = -L2E * (bih0[c] + bhh0[c]);
        const float bZ  = -L2E * (bih0[128 + c] + bhh0[128 + c]);
        bf16x8 wI[3][2];
        i32x4  wH[3][2];
        #pragma unroll
        for (int g = 0; g < 3; ++g) {
            const int row = g * 128 + c;
            const float sc = (g == 2) ? (-2.f * L2E) : (-L2E);
            #pragma unroll
            for (int q = 0; q < 2; ++q) {
                wI[g][q] = wfrag_bf(Wih0, 64, row, q * 32 + q8, sc);
                wH[g][q] = wfrag_i8(Whh0, 128, row, q * 64 + q16);
            }
        }

        // staging: 256 loaders (lanes 0..31 of each wave)
        const bool loader = (lane < 32);
        const int lidx = wave * 32 + lane;
        const int sb = (lidx >> 6) & 3, scg = lidx & 63;
        const float* xp = x + (size_t)(brow + sb) * T_LEN * 64 + scg;
        float vx0 = 0.f, vx1 = 0.f, vx2 = 0.f;
        if (loader) {
            #pragma unroll
            for (int tq = 0; tq < 4; ++tq)
                xg[0][(tq + 4 * sb) * XS + scg] = (__bf16)xp[(size_t)tq * 64];
            vx0 = xp[4 * 64];
            vx1 = xp[5 * 64];
            vx2 = xp[6 * 64];
        }
        __syncthreads();              // publish xg[0]

        float hfv = 0.f;
        floatx4 pR, pZ, pNi;
        for (int G = 0; G <= NG; ++G) {
            const bool act = (G < NG);
            #pragma unroll
            for (int p = 0; p < 4; ++p) {
                const int tt = 4 * G + p;
                __builtin_amdgcn_sched_barrier(0);
                BARRIER_LDS();        // per-step barrier (lgkm only)
                // publish flag for group G-1 (all lanes' stores drained at the
                // p==3 vmcnt(0) before this barrier; wbl2 from the release
                // pushes them to the coherent point).
                if (p == 0 && G >= 1 && tid == 0)
                    __hip_atomic_store(&fl[G - 1], 1u,
                                       __ATOMIC_RELEASE, __HIP_MEMORY_SCOPE_AGENT);
                if (loader) {
                    if (tt + 4 < T_LEN)
                        xg[(G + 1) & 1][(p + 4 * sb) * XS + scg] = (__bf16)vx0;
                    vx0 = vx1; vx1 = vx2;
                    int tl = tt + 7; if (tl > T_LEN - 1) tl = T_LEN - 1;
                    vx2 = xp[(size_t)tl * 64];
                }
                if (act) {
                    if (p == 0) {     // group x-side GEMM: steps 4G..4G+3
                        bf16x8 ax0 = *(const bf16x8*)&xg[G & 1][ln16 * XS + q8];
                        bf16x8 ax1 = *(const bf16x8*)&xg[G & 1][ln16 * XS + 32 + q8];
                        floatx4 fR  = {bR, bR, bR, bR};
                        floatx4 fZ  = {bZ, bZ, bZ, bZ};
                        floatx4 fNi = {bNi, bNi, bNi, bNi};
                        __builtin_amdgcn_s_setprio(1);
                        fR  = MFMA_BF(ax0, wI[0][0], fR);  fR  = MFMA_BF(ax1, wI[0][1], fR);
                        fZ  = MFMA_BF(ax0, wI[1][0], fZ);  fZ  = MFMA_BF(ax1, wI[1][1], fZ);
                        fNi = MFMA_BF(ax0, wI[2][0], fNi); fNi = MFMA_BF(ax1, wI[2][1], fNi);
                        __builtin_amdgcn_s_setprio(0);
                        pR = fR; pZ = fZ; pNi = fNi;
                    }
                    const int Rp = (tt + 1) & 1, Wc = tt & 1;
                    i32x4 ah[2];
                    #pragma unroll
                    for (int q = 0; q < 2; ++q)
                        ah[q] = *(const i32x4*)&h0b[Rp][ln16 * HIS + q * 64 + q16];
                    i32x4 cR = {0,0,0,0}, cZ = {0,0,0,0}, cNh = {0,0,0,0};
                    __builtin_amdgcn_s_setprio(1);
                    #pragma unroll
                    for (int q = 0; q < 2; ++q) {
                        cR  = MFMA_I8(ah[q], wH[0][q], cR);
                        cZ  = MFMA_I8(ah[q], wH[1][q], cZ);
                        cNh = MFMA_I8(ah[q], wH[2][q], cNh);
                    }
                    __builtin_amdgcn_s_setprio(0);
                    const float pr  = fmaf((float)cR[0],  S_RZ, pR[p]);
                    const float pz  = fmaf((float)cZ[0],  S_RZ, pZ[p]);
                    const float phn = fmaf((float)cNh[0], S_N,  bNh);
                    const float r = rcpf(1.f + EXP2(pr));
                    const float z = rcpf(1.f + EXP2(pz));
                    const float n = 2.f * rcpf(1.f + EXP2(fmaf(r, phn, pNi[p]))) - 1.f;
                    const float h = n + z * (hfv - n);
                    hfv = h;
                    const signed char qv = (signed char)(int)__builtin_rintf(h * 127.f);
                    h0b[Wc][(quad * 4) * HIS + c] = qv;              // own recurrence
                    gb[(size_t)G * GB_GROUP + (p + 4 * quad) * 128 + c] = qv;  // stream to L1
                    if (p == 3)       // drain this group's global writes
                        asm volatile("s_waitcnt vmcnt(0)" ::: "memory");
                }
            }
        }
    } else {
        // ===== consumer: layer-1 (lag 12), cols [16w,16w+16) =====
        const int c = wave * 16 + ln16;
        const float bNi1 = -2.f * L2E * bih1[256 + c];
        const float bNh1 = -2.f * L2E * bhh1[256 + c];
        const float bR1  = -L2E * (bih1[c] + bhh1[c]);
        const float bZ1  = -L2E * (bih1[128 + c] + bhh1[128 + c]);
        i32x4 wI[3][2], wH[3][2];
        #pragma unroll
        for (int g = 0; g < 3; ++g) {
            const int row = g * 128 + c;
            #pragma unroll
            for (int q = 0; q < 2; ++q) {
                wI[g][q] = wfrag_i8(Wih1, 128, row, q * 64 + q16);
                wH[g][q] = wfrag_i8(Whh1, 128, row, q * 64 + q16);
            }
        }

        float hfv = 0.f;
        i32x4 gR = {0,0,0,0}, gZ = {0,0,0,0}, gNi = {0,0,0,0};
        i32x4 gaA0 = {0,0,0,0}, gaA1 = {0,0,0,0};   // group in use (h0 grp G-3)
        i32x4 gaB0 = {0,0,0,0}, gaB1 = {0,0,0,0};   // preloaded (h0 grp G-2)
        for (int G = 0; G <= NG + 2; ++G) {
            #pragma unroll
            for (int p = 0; p < 4; ++p) {
                __builtin_amdgcn_sched_barrier(0);
                BARRIER_LDS();        // orders h1b double-buffer
                if (p == 0 && G >= 2 && G - 2 < NG) {
                    const int gidx = G - 2;   // poll + preload (used 4 intervals later)
                    while (__hip_atomic_load(&fl[gidx],
                             __ATOMIC_ACQUIRE, __HIP_MEMORY_SCOPE_AGENT) == 0u)
                        __builtin_amdgcn_s_sleep(2);
                    const signed char* gp = gb + (size_t)gidx * GB_GROUP + ln16 * 128 + q16;
                    gaB0 = *(const i32x4*)(gp);
                    gaB1 = *(const i32x4*)(gp + 64);
                }
                const int s = 4 * (G - 3) + p;    // L1 step this interval
                if (s >= 0) {
                    if (p == 0) {     // group input-side GEMM on h0 group G-3
                        i32x4 aR = {0,0,0,0}, aZ = {0,0,0,0}, aN = {0,0,0,0};
                        __builtin_amdgcn_s_setprio(1);
                        aR = MFMA_I8(gaA0, wI[0][0], aR); aR = MFMA_I8(gaA1, wI[0][1], aR);
                        aZ = MFMA_I8(gaA0, wI[1][0], aZ); aZ = MFMA_I8(gaA1, wI[1][1], aZ);
                        aN = MFMA_I8(gaA0, wI[2][0], aN); aN = MFMA_I8(gaA1, wI[2][1], aN);
                        __builtin_amdgcn_s_setprio(0);
                        gR = aR; gZ = aZ; gNi = aN;
                    }
                    const int Rp = (s + 1) & 1, Wc = s & 1;
                    i32x4 a1[2];
                    #pragma unroll
                    for (int q = 0; q < 2; ++q)
                        a1[q] = *(const i32x4*)&h1b[Rp][ln16 * HIS + q * 64 + q16];
                    i32x4 cR = {0,0,0,0}, cZ = {0,0,0,0}, cNh = {0,0,0,0};
                    __builtin_amdgcn_s_setprio(1);
                    #pragma unroll
                    for (int q = 0; q < 2; ++q) {
                        cR  = MFMA_I8(a1[q], wH[0][q], cR);
                        cZ  = MFMA_I8(a1[q], wH[1][q], cZ);
                        cNh = MFMA_I8(a1[q], wH[2][q], cNh);
                    }
                    __builtin_amdgcn_s_setprio(0);
                    const float pr  = fmaf((float)(cR[0] + gR[p]), S_RZ, bR1);
                    const float pz  = fmaf((float)(cZ[0] + gZ[p]), S_RZ, bZ1);
                    const float pin = fmaf((float)gNi[p], S_N, bNi1);
                    const float phn = fmaf((float)cNh[0], S_N, bNh1);
                    const float r = rcpf(1.f + EXP2(pr));
                    const float z = rcpf(1.f + EXP2(pz));
                    const float n = 2.f * rcpf(1.f + EXP2(fmaf(r, phn, pin))) - 1.f;
                    const float h = n + z * (hfv - n);
                    hfv = h;
                    h1b[Wc][(quad * 4) * HIS + c] =
                        (signed char)(int)__builtin_rintf(h * 127.f);
                }
                if (p == 3 && G >= 2 && G - 2 < NG) {   // rollover preloaded group
                    gaA0 = gaB0; gaA1 = gaB1;
                }
            }
        }
        hfin[(quad * 4) * HFS + c] = hfv;
    }

    __syncthreads();
    // final FC (consumer blocks only): out[b] = h1(T-1)[b,:] . Wfc + bfc
    if (role == 1) {
        const int row = tid >> 5, l = tid & 31;
        if (row < 16 && (row & 3) == 0) {
            float s = 0.f;
            #pragma unroll
            for (int k = 0; k < 4; ++k)
                s += hfin[row * HFS + l + 32 * k] * Wfc[l + 32 * k];
            #pragma unroll
            for (int d = 16; d >= 1; d >>= 1) s += __shfl_down(s, d, 32);
            if (l == 0) out[brow + (row >> 2)] = s + bfc[0];
        }
    }
}

// ===========================================================================
// Fallback: exact round-9 monolithic kernel (best measured 267.6 us rocprof),
// used when ws_size < WS_NEEDED.
// ===========================================================================
__global__ __launch_bounds__(1024, 4) void gru_fused_mono(
    const float* __restrict__ x,
    const float* __restrict__ Wih0, const float* __restrict__ Whh0,
    const float* __restrict__ bih0, const float* __restrict__ bhh0,
    const float* __restrict__ Wih1, const float* __restrict__ Whh1,
    const float* __restrict__ bih1, const float* __restrict__ bhh1,
    const float* __restrict__ Wfc,  const float* __restrict__ bfc,
    float* __restrict__ out)
{
    __shared__ __align__(16) __bf16      xg[2][16 * XS];
    __shared__ __align__(16) signed char h0b[2][16 * HIS];
    __shared__ __align__(16) signed char h0g[2][16 * HIS];
    __shared__ __align__(16) signed char h1b[2][16 * HIS];
    __shared__ __align__(16) float       hfin[16 * HFS];

    const int tid  = threadIdx.x;
    const int lane = tid & 63;
    const int ln16 = lane & 15;
    const int quad = lane >> 4;
    const int q8   = quad * 8;
    const int q16  = quad * 16;
    const int wave = tid >> 6;
    const int brow = blockIdx.x * BT;

    for (int i = tid; i < 16 * HIS; i += 1024) {
        h0b[0][i] = 0; h0b[1][i] = 0;
        h0g[0][i] = 0; h0g[1][i] = 0;
        h1b[0][i] = 0; h1b[1][i] = 0;
    }
    for (int i = tid; i < 16 * XS; i += 1024) {
        xg[0][i] = (__bf16)0.f; xg[1][i] = (__bf16)0.f;
    }
    __syncthreads();

    if (wave < 8) {
        const int c = wave * 16 + ln16;
        const float bNi = -2.f * L2E * bih0[256 + c];
        const float bNh = -2.f * L2E * bhh0[256 + c];
        const float bR  = -L2E * (bih0[c] + bhh0[c]);
        const float bZ  = -L2E * (bih0[128 + c] + bhh0[128 + c]);
        bf16x8 wI[3][2];
        i32x4  wH[3][2];
        #pragma unroll
        for (int g = 0; g < 3; ++g) {
            const int row = g * 128 + c;
            const float sc = (g == 2) ? (-2.f * L2E) : (-L2E);
            #pragma unroll
            for (int q = 0; q < 2; ++q) {
                wI[g][q] = wfrag_bf(Wih0, 64, row, q * 32 + q8, sc);
                wH[g][q] = wfrag_i8(Whh0, 128, row, q * 64 + q16);
            }
        }
        const bool loader = (lane < 32);
        const int lidx = wave * 32 + lane;
        const int sb = (lidx >> 6) & 3, scg = lidx & 63;
        const float* xp = x + (size_t)(brow + sb) * T_LEN * 64 + scg;
        float vx0 = 0.f, vx1 = 0.f, vx2 = 0.f;
        if (loader) {
            #pragma unroll
            for (int tq = 0; tq < 4; ++tq)
                xg[0][(tq + 4 * sb) * XS + scg] = (__bf16)xp[(size_t)tq * 64];
            vx0 = xp[4 * 64]; vx1 = xp[5 * 64]; vx2 = xp[6 * 64];
        }
        __syncthreads();

        float hfv = 0.f;
        floatx4 pR, pZ, pNi;
        for (int G = 0; G <= NG; ++G) {
            const bool act = (G < NG);
            #pragma unroll
            for (int p = 0; p < 4; ++p) {
                const int tt = 4 * G + p;
                __builtin_amdgcn_sched_barrier(0);
                BARRIER_LDS();
                if (loader) {
                    if (tt + 4 < T_LEN)
                        xg[(G + 1) & 1][(p + 4 * sb) * XS + scg] = (__bf16)vx0;
                    vx0 = vx1; vx1 = vx2;
                    int tl = tt + 7; if (tl > T_LEN - 1) tl = T_LEN - 1;
                    vx2 = xp[(size_t)tl * 64];
                }
                if (act) {
                    if (p == 0) {
                        bf16x8 ax0 = *(const bf16x8*)&xg[G & 1][ln16 * XS + q8];
                        bf16x8 ax1 = *(const bf16x8*)&xg[G & 1][ln16 * XS + 32 + q8];
                        floatx4 fR  = {bR, bR, bR, bR};
                        floatx4 fZ  = {bZ, bZ, bZ, bZ};
                        floatx4 fNi = {bNi, bNi, bNi, bNi};
                        __builtin_amdgcn_s_setprio(1);
                        fR  = MFMA_BF(ax0, wI[0][0], fR);  fR  = MFMA_BF(ax1, wI[0][1], fR);
                        fZ  = MFMA_BF(ax0, wI[1][0], fZ);  fZ  = MFMA_BF(ax1, wI[1][1], fZ);
                        fNi = MFMA_BF(ax0, wI[2][0], fNi); fNi = MFMA_BF(ax1, wI[2][1], fNi);
                        __builtin_amdgcn_s_setprio(0);
                        pR = fR; pZ = fZ; pNi = fNi;
                    }
                    const int Rp = (tt + 1) & 1, Wc = tt & 1;
                    i32x4 ah[2];
                    #pragma unroll
                    for (int q = 0; q < 2; ++q)
                        ah[q] = *(const i32x4*)&h0b[Rp][ln16 * HIS + q * 64 + q16];
                    i32x4 cR = {0,0,0,0}, cZ = {0,0,0,0}, cNh = {0,0,0,0};
                    __builtin_amdgcn_s_setprio(1);
                    #pragma unroll
                    for (int q = 0; q < 2; ++q) {
                        cR  = MFMA_I8(ah[q], wH[0][q], cR);
                        cZ  = MFMA_I8(ah[q], wH[1][q], cZ);
                        cNh = MFMA_I8(ah[q], wH[2][q], cNh);
                    }
                    __builtin_amdgcn_s_setprio(0);
                    const float pr  = fmaf((float)cR[0],  S_RZ, pR[p]);
                    const float pz  = fmaf((float)cZ[0],  S_RZ, pZ[p]);
                    const float phn = fmaf((float)cNh[0], S_N,  bNh);
                    const float r = rcpf(1.f + EXP2(pr));
                    const float z = rcpf(1.f + EXP2(pz));
                    const float n = 2.f * rcpf(1.f + EXP2(fmaf(r, phn, pNi[p]))) - 1.f;
                    const float h = n + z * (hfv - n);
                    hfv = h;
                    const signed char qv = (signed char)(int)__builtin_rintf(h * 127.f);
                    h0b[Wc][(quad * 4) * HIS + c] = qv;
                    h0g[G & 1][(p + 4 * quad) * HIS + c] = qv;
                }
            }
        }
    } else {
        const int wv = wave - 8;
        const int c  = wv * 16 + ln16;
        const float bNi1 = -2.f * L2E * bih1[256 + c];
        const float bNh1 = -2.f * L2E * bhh1[256 + c];
        const float bR1  = -L2E * (bih1[c] + bhh1[c]);
        const float bZ1  = -L2E * (bih1[128 + c] + bhh1[128 + c]);
        i32x4 wI[3][2], wH[3][2];
        #pragma unroll
        for (int g = 0; g < 3; ++g) {
            const int row = g * 128 + c;
            #pragma unroll
            for (int q = 0; q < 2; ++q) {
                wI[g][q] = wfrag_i8(Wih1, 128, row, q * 64 + q16);
                wH[g][q] = wfrag_i8(Whh1, 128, row, q * 64 + q16);
            }
        }
        __syncthreads();

        float hfv = 0.f;
        i32x4 gR, gZ, gNi;
        for (int G = 0; G <= NG; ++G) {
            const bool act = (G >= 1);
            #pragma unroll
            for (int p = 0; p < 4; ++p) {
                __builtin_amdgcn_sched_barrier(0);
                BARRIER_LDS();
                if (act) {
                    if (p == 0) {
                        i32x4 ag[2];
                        #pragma unroll
                        for (int q = 0; q < 2; ++q)
                            ag[q] = *(const i32x4*)&h0g[(G - 1) & 1][ln16 * HIS + q * 64 + q16];
                        i32x4 aR = {0,0,0,0}, aZ = {0,0,0,0}, aN = {0,0,0,0};
                        __builtin_amdgcn_s_setprio(1);
                        #pragma unroll
                        for (int q = 0; q < 2; ++q) {
                            aR = MFMA_I8(ag[q], wI[0][q], aR);
                            aZ = MFMA_I8(ag[q], wI[1][q], aZ);
                            aN = MFMA_I8(ag[q], wI[2][q], aN);
                        }
                        __builtin_amdgcn_s_setprio(0);
                        gR = aR; gZ = aZ; gNi = aN;
                    }
                    const int s  = 4 * (G - 1) + p;
                    const int Rp = (s + 1) & 1, Wc = s & 1;
                    i32x4 a1[2];
                    #pragma unroll
                    for (int q = 0; q < 2; ++q)
                        a1[q] = *(const i32x4*)&h1b[Rp][ln16 * HIS + q * 64 + q16];
                    i32x4 cR = {0,0,0,0}, cZ = {0,0,0,0}, cNh = {0,0,0,0};
                    __builtin_amdgcn_s_setprio(1);
                    #pragma unroll
                    for (int q = 0; q < 2; ++q) {
                        cR  = MFMA_I8(a1[q], wH[0][q], cR);
                        cZ  = MFMA_I8(a1[q], wH[1][q], cZ);
                        cNh = MFMA_I8(a1[q], wH[2][q], cNh);
                    }
                    __builtin_amdgcn_s_setprio(0);
                    const float pr  = fmaf((float)(cR[0] + gR[p]), S_RZ, bR1);
                    const float pz  = fmaf((float)(cZ[0] + gZ[p]), S_RZ, bZ1);
                    const float pin = fmaf((float)gNi[p], S_N, bNi1);
                    const float phn = fmaf((float)cNh[0], S_N, bNh1);
                    const float r = rcpf(1.f + EXP2(pr));
                    const float z = rcpf(1.f + EXP2(pz));
                    const float n = 2.f * rcpf(1.f + EXP2(fmaf(r, phn, pin))) - 1.f;
                    const float h = n + z * (hfv - n);
                    hfv = h;
                    h1b[Wc][(quad * 4) * HIS + c] =
                        (signed char)(int)__builtin_rintf(h * 127.f);
                }
            }
        }
        hfin[(quad * 4) * HFS + c] = hfv;
    }

    __syncthreads();
    {
        const int row = tid >> 5, l = tid & 31;
        if (row < 16 && (row & 3) == 0) {
            float s = 0.f;
            #pragma unroll
            for (int k = 0; k < 4; ++k)
                s += hfin[row * HFS + l + 32 * k] * Wfc[l + 32 * k];
            #pragma unroll
            for (int d = 16; d >= 1; d >>= 1) s += __shfl_down(s, d, 32);
            if (l == 0) out[brow + (row >> 2)] = s + bfc[0];
        }
    }
}

extern "C" void kernel_launch(void* const* d_in, const int* in_sizes, int n_in,
                              void* d_out, int out_size, void* d_ws, size_t ws_size,
                              hipStream_t stream) {
    const float* x    = (const float*)d_in[0];
    const float* Wih0 = (const float*)d_in[1];
    const float* Whh0 = (const float*)d_in[2];
    const float* bih0 = (const float*)d_in[3];
    const float* bhh0 = (const float*)d_in[4];
    const float* Wih1 = (const float*)d_in[5];
    const float* Whh1 = (const float*)d_in[6];
    const float* bih1 = (const float*)d_in[7];
    const float* bhh1 = (const float*)d_in[8];
    const float* Wfc  = (const float*)d_in[9];
    const float* bfc  = (const float*)d_in[10];
    float* out = (float*)d_out;

    if (d_ws != nullptr && ws_size >= WS_NEEDED) {
        unsigned*    flags = (unsigned*)d_ws;
        signed char* gdata = (signed char*)d_ws + WS_FLAGS;
        hipMemsetAsync(d_ws, 0, WS_FLAGS, stream);   // zero flags (graph-capturable)
        hipLaunchKernelGGL(gru_split, dim3(256), dim3(512), 0, stream,
                           x, Wih0, Whh0, bih0, bhh0, Wih1, Whh1, bih1, bhh1,
                           Wfc, bfc, out, flags, gdata);
    } else {
        hipLaunchKernelGGL(gru_fused_mono, dim3(512 / BT), dim3(1024), 0, stream,
                           x, Wih0, Whh0, bih0, bhh0, Wih1, Whh1, bih1, bhh1,
                           Wfc, bfc, out);
    }
}

// Round 12
// 345.285 us; speedup vs baseline: 4.2251x; 4.2251x over previous
//
#include <hip/hip_runtime.h>
#include <stdint.h>

typedef __bf16 bf16x8 __attribute__((ext_vector_type(8)));
typedef float  floatx4 __attribute__((ext_vector_type(4)));
typedef int    i32x4  __attribute__((ext_vector_type(4)));

#define T_LEN 512
#define NG    (T_LEN / 4)   // 128 time-groups of 4 steps
#define BT    4             // batch rows per block -> 128 blocks
#define NTHR  1024          // 16 waves: 0-7 = layer0 (+x staging), 8-15 = layer1
#define XS    72            // x group-tile row stride (bf16)
#define HIS   144           // h int8 LDS row stride (bytes)
#define HFS   132           // final h1 fp32 row stride

#if __has_builtin(__builtin_amdgcn_exp2f)
#define EXP2(x) __builtin_amdgcn_exp2f(x)
#else
#define EXP2(x) exp2f(x)
#endif

#define MFMA_BF(a,b,c)  __builtin_amdgcn_mfma_f32_16x16x32_bf16((a),(b),(c),0,0,0)
#define MFMA_I8(a,b,c)  __builtin_amdgcn_mfma_i32_16x16x64_i8((a),(b),(c),0,0,0)

// Raw workgroup barrier: drains LDS ops only (lgkmcnt), NOT vmcnt — global
// x-prefetch loads stay in flight across barriers.
#define BARRIER_LDS() asm volatile("s_waitcnt lgkmcnt(0)\n\ts_barrier" ::: "memory")

// quantization: h -> q*1/127 ; w -> q*1/254 (|w| clamped at 0.5)
#define L2E   1.4426950408889634f
#define S_RZ  (-L2E / (254.f * 127.f))        // i32 -> -log2e * preact
#define S_N   (-2.f * L2E / (254.f * 127.f))  // i32 -> -2*log2e * preact

__device__ __forceinline__ float rcpf(float x) { return __builtin_amdgcn_rcpf(x); }

__device__ __forceinline__ bf16x8 wfrag_bf(const float* W, int ldk, int row, int k0, float scale) {
    const float* p = W + (size_t)row * ldk + k0;
    bf16x8 r;
    #pragma unroll
    for (int j = 0; j < 8; ++j) r[j] = (__bf16)(p[j] * scale);
    return r;
}
__device__ __forceinline__ i32x4 wfrag_i8(const float* W, int ldk, int row, int k0) {
    const float* p = W + (size_t)row * ldk + k0;
    i32x4 r;
    #pragma unroll
    for (int d = 0; d < 4; ++d) {
        uint32_t dw = 0;
        #pragma unroll
        for (int j = 0; j < 4; ++j) {
            float q = __builtin_rintf(p[d * 4 + j] * 254.f);
            q = fminf(127.f, fmaxf(-127.f, q));
            dw |= ((uint32_t)((int)q & 0xff)) << (8 * j);
        }
        r[d] = (int)dw;
    }
    return r;
}

// FINAL KERNEL = exact round-9 source (session best: 267.6 us rocprof).
// Round 11's cross-block producer/consumer split regressed 5x (agent-scope
// release/acquire handshake is ~11 us/group vs ~0.55 us of compute saved):
// fine-grained cross-CU sync cannot carry this recurrence. Reverting.
//   Structure: 128 blocks x 16 waves (L0 waves 0-7 + x staging, L1 waves
//   8-15 at group lag 4). Feed-forward GEMMs time-batched (16-row A-tile =
//   4 timesteps x 4 batch rows, row = p+4b); hidden GEMMs sequential int8
//   K=64. ONE lgkm-only barrier per step; 3-deep x register prefetch;
//   setprio(1) around MFMA clusters. absmax 0.01806641.
// Measured budget/interval (~1245 cy): ~610 MFMA issue (tile-count bound),
// ~345 serial gate chain, ~290 LDS turnaround/bank-alias/skew. Active-CU
// issue saturation ~92% -> structural roofline of the barrier-locked
// recurrence at BT=4.
__global__ __launch_bounds__(NTHR, 4) void gru_fused(
    const float* __restrict__ x,
    const float* __restrict__ Wih0, const float* __restrict__ Whh0,
    const float* __restrict__ bih0, const float* __restrict__ bhh0,
    const float* __restrict__ Wih1, const float* __restrict__ Whh1,
    const float* __restrict__ bih1, const float* __restrict__ bhh1,
    const float* __restrict__ Wfc,  const float* __restrict__ bfc,
    float* __restrict__ out)
{
    __shared__ __align__(16) __bf16      xg[2][16 * XS];    // x group tile (p+4b rows)
    __shared__ __align__(16) signed char h0b[2][16 * HIS];  // h0 b-major (L0 hidden)
    __shared__ __align__(16) signed char h0g[2][16 * HIS];  // h0 group tile (L1 input)
    __shared__ __align__(16) signed char h1b[2][16 * HIS];  // h1 b-major (L1 hidden)
    __shared__ __align__(16) float       hfin[16 * HFS];

    const int tid  = threadIdx.x;
    const int lane = tid & 63;
    const int ln16 = lane & 15;
    const int quad = lane >> 4;
    const int q8   = quad * 8;        // bf16 k-offset (elements)
    const int q16  = quad * 16;       // int8 k-offset (bytes)
    const int wave = tid >> 6;        // 0..15
    const int brow = blockIdx.x * BT;

    for (int i = tid; i < 16 * HIS; i += NTHR) {
        h0b[0][i] = 0; h0b[1][i] = 0;
        h0g[0][i] = 0; h0g[1][i] = 0;
        h1b[0][i] = 0; h1b[1][i] = 0;
    }
    for (int i = tid; i < 16 * XS; i += NTHR) {
        xg[0][i] = (__bf16)0.f; xg[1][i] = (__bf16)0.f;
    }
    __syncthreads();                  // init barrier

    if (wave < 8) {
        // ===== layer-0: cols [16w,16w+16); x-side bf16 (time-batched), hidden i8 =====
        const int c = wave * 16 + ln16;
        const float bNi = -2.f * L2E * bih0[256 + c];
        const float bNh = -2.f * L2E * bhh0[256 + c];
        const float bR  = -L2E * (bih0[c] + bhh0[c]);
        const float bZ  = -L2E * (bih0[128 + c] + bhh0[128 + c]);
        bf16x8 wI[3][2];              // x-side, scale-folded
        i32x4  wH[3][2];              // hidden int8 K=64
        #pragma unroll
        for (int g = 0; g < 3; ++g) {
            const int row = g * 128 + c;
            const float sc = (g == 2) ? (-2.f * L2E) : (-L2E);
            #pragma unroll
            for (int q = 0; q < 2; ++q) {
                wI[g][q] = wfrag_bf(Wih0, 64, row, q * 32 + q8, sc);
                wH[g][q] = wfrag_i8(Whh0, 128, row, q * 64 + q16);
            }
        }

        // staging: 256 loaders (lanes 0..31 of each L0 wave)
        const bool loader = (lane < 32);
        const int lidx = wave * 32 + lane;
        const int sb = (lidx >> 6) & 3, scg = lidx & 63;
        const float* xp = x + (size_t)(brow + sb) * T_LEN * 64 + scg;
        float vx0 = 0.f, vx1 = 0.f, vx2 = 0.f;
        if (loader) {
            // prologue: x(0..3) -> xg[0] rows tq+4*sb; prefetch x(4..6)
            #pragma unroll
            for (int tq = 0; tq < 4; ++tq)
                xg[0][(tq + 4 * sb) * XS + scg] = (__bf16)xp[(size_t)tq * 64];
            vx0 = xp[4 * 64];
            vx1 = xp[5 * 64];
            vx2 = xp[6 * 64];
        }
        __syncthreads();              // publish xg[0]

        float hfv = 0.f;
        floatx4 pR, pZ, pNi;          // group x-side accs: acc[p] = step 4G+p
        for (int G = 0; G <= NG; ++G) {
            const bool act = (G < NG);
            #pragma unroll
            for (int p = 0; p < 4; ++p) {
                const int tt = 4 * G + p;
                __builtin_amdgcn_sched_barrier(0);
                BARRIER_LDS();        // the ONLY per-step barrier (lgkm only)
                // staging: write x(tt+4) into xg[(G+1)&1] row p+4*sb
                if (loader) {
                    if (tt + 4 < T_LEN)
                        xg[(G + 1) & 1][(p + 4 * sb) * XS + scg] = (__bf16)vx0;
                    vx0 = vx1; vx1 = vx2;
                    int tl = tt + 7; if (tl > T_LEN - 1) tl = T_LEN - 1;
                    vx2 = xp[(size_t)tl * 64];
                }
                if (act) {
                    if (p == 0) {     // group x-side GEMM: steps 4G..4G+3
                        bf16x8 ax0 = *(const bf16x8*)&xg[G & 1][ln16 * XS + q8];
                        bf16x8 ax1 = *(const bf16x8*)&xg[G & 1][ln16 * XS + 32 + q8];
                        floatx4 fR  = {bR, bR, bR, bR};
                        floatx4 fZ  = {bZ, bZ, bZ, bZ};
                        floatx4 fNi = {bNi, bNi, bNi, bNi};
                        __builtin_amdgcn_s_setprio(1);
                        fR  = MFMA_BF(ax0, wI[0][0], fR);  fR  = MFMA_BF(ax1, wI[0][1], fR);
                        fZ  = MFMA_BF(ax0, wI[1][0], fZ);  fZ  = MFMA_BF(ax1, wI[1][1], fZ);
                        fNi = MFMA_BF(ax0, wI[2][0], fNi); fNi = MFMA_BF(ax1, wI[2][1], fNi);
                        __builtin_amdgcn_s_setprio(0);
                        pR = fR; pZ = fZ; pNi = fNi;
                    }
                    // hidden side of step tt (sequential)
                    const int Rp = (tt + 1) & 1, Wc = tt & 1;
                    i32x4 ah[2];
                    #pragma unroll
                    for (int q = 0; q < 2; ++q)
                        ah[q] = *(const i32x4*)&h0b[Rp][ln16 * HIS + q * 64 + q16];
                    i32x4 cR = {0,0,0,0}, cZ = {0,0,0,0}, cNh = {0,0,0,0};
                    __builtin_amdgcn_s_setprio(1);
                    #pragma unroll
                    for (int q = 0; q < 2; ++q) {
                        cR  = MFMA_I8(ah[q], wH[0][q], cR);
                        cZ  = MFMA_I8(ah[q], wH[1][q], cZ);
                        cNh = MFMA_I8(ah[q], wH[2][q], cNh);
                    }
                    __builtin_amdgcn_s_setprio(0);
                    // gate math; x-side value for this step = acc reg p
                    const float pr  = fmaf((float)cR[0],  S_RZ, pR[p]);
                    const float pz  = fmaf((float)cZ[0],  S_RZ, pZ[p]);
                    const float phn = fmaf((float)cNh[0], S_N,  bNh);
                    const float r = rcpf(1.f + EXP2(pr));
                    const float z = rcpf(1.f + EXP2(pz));
                    const float n = 2.f * rcpf(1.f + EXP2(fmaf(r, phn, pNi[p]))) - 1.f;
                    const float h = n + z * (hfv - n);
                    hfv = h;
                    const signed char qv = (signed char)(int)__builtin_rintf(h * 127.f);
                    h0b[Wc][(quad * 4) * HIS + c] = qv;          // for L0 hidden (t+1)
                    h0g[G & 1][(p + 4 * quad) * HIS + c] = qv;   // group tile for L1
                }
            }
        }
    } else {
        // ===== layer-1 (group lag 4): cols [16wv,16wv+16); all int8 =====
        const int wv = wave - 8;
        const int c  = wv * 16 + ln16;
        const float bNi1 = -2.f * L2E * bih1[256 + c];
        const float bNh1 = -2.f * L2E * bhh1[256 + c];
        const float bR1  = -L2E * (bih1[c] + bhh1[c]);
        const float bZ1  = -L2E * (bih1[128 + c] + bhh1[128 + c]);
        i32x4 wI[3][2], wH[3][2];
        #pragma unroll
        for (int g = 0; g < 3; ++g) {
            const int row = g * 128 + c;
            #pragma unroll
            for (int q = 0; q < 2; ++q) {
                wI[g][q] = wfrag_i8(Wih1, 128, row, q * 64 + q16);
                wH[g][q] = wfrag_i8(Whh1, 128, row, q * 64 + q16);
            }
        }
        __syncthreads();              // match L0's xg-publish barrier

        float hfv = 0.f;
        i32x4 gR, gZ, gNi;            // group input-side accs: acc[p] = step 4(G-1)+p
        for (int G = 0; G <= NG; ++G) {
            const bool act = (G >= 1);
            #pragma unroll
            for (int p = 0; p < 4; ++p) {
                __builtin_amdgcn_sched_barrier(0);
                BARRIER_LDS();
                if (act) {
                    if (p == 0) {     // group input-side GEMM on h0(4(G-1)..4(G-1)+3)
                        i32x4 ag[2];
                        #pragma unroll
                        for (int q = 0; q < 2; ++q)
                            ag[q] = *(const i32x4*)&h0g[(G - 1) & 1][ln16 * HIS + q * 64 + q16];
                        i32x4 aR = {0,0,0,0}, aZ = {0,0,0,0}, aN = {0,0,0,0};
                        __builtin_amdgcn_s_setprio(1);
                        #pragma unroll
                        for (int q = 0; q < 2; ++q) {
                            aR = MFMA_I8(ag[q], wI[0][q], aR);
                            aZ = MFMA_I8(ag[q], wI[1][q], aZ);
                            aN = MFMA_I8(ag[q], wI[2][q], aN);
                        }
                        __builtin_amdgcn_s_setprio(0);
                        gR = aR; gZ = aZ; gNi = aN;
                    }
                    // hidden side of L1 step s = 4(G-1)+p (sequential)
                    const int s  = 4 * (G - 1) + p;
                    const int Rp = (s + 1) & 1, Wc = s & 1;
                    i32x4 a1[2];
                    #pragma unroll
                    for (int q = 0; q < 2; ++q)
                        a1[q] = *(const i32x4*)&h1b[Rp][ln16 * HIS + q * 64 + q16];
                    i32x4 cR = {0,0,0,0}, cZ = {0,0,0,0}, cNh = {0,0,0,0};
                    __builtin_amdgcn_s_setprio(1);
                    #pragma unroll
                    for (int q = 0; q < 2; ++q) {
                        cR  = MFMA_I8(a1[q], wH[0][q], cR);
                        cZ  = MFMA_I8(a1[q], wH[1][q], cZ);
                        cNh = MFMA_I8(a1[q], wH[2][q], cNh);
                    }
                    __builtin_amdgcn_s_setprio(0);
                    // gate math; input-side value = group acc reg p (exact i32 add)
                    const float pr  = fmaf((float)(cR[0] + gR[p]), S_RZ, bR1);
                    const float pz  = fmaf((float)(cZ[0] + gZ[p]), S_RZ, bZ1);
                    const float pin = fmaf((float)gNi[p], S_N, bNi1);
                    const float phn = fmaf((float)cNh[0], S_N, bNh1);
                    const float r = rcpf(1.f + EXP2(pr));
                    const float z = rcpf(1.f + EXP2(pz));
                    const float n = 2.f * rcpf(1.f + EXP2(fmaf(r, phn, pin))) - 1.f;
                    const float h = n + z * (hfv - n);
                    hfv = h;
                    h1b[Wc][(quad * 4) * HIS + c] =
                        (signed char)(int)__builtin_rintf(h * 127.f);
                }
            }
        }
        // publish final h1 (fp32 state) for the FC epilogue
        hfin[(quad * 4) * HFS + c] = hfv;
    }

    __syncthreads();
    // final FC: out[b] = h1(T-1)[b,:] . Wfc + bfc  (tile rows 0,4,8,12)
    {
        const int row = tid >> 5, l = tid & 31;
        if (row < 16 && (row & 3) == 0) {
            float s = 0.f;
            #pragma unroll
            for (int k = 0; k < 4; ++k)
                s += hfin[row * HFS + l + 32 * k] * Wfc[l + 32 * k];
            #pragma unroll
            for (int d = 16; d >= 1; d >>= 1) s += __shfl_down(s, d, 32);
            if (l == 0) out[brow + (row >> 2)] = s + bfc[0];
        }
    }
}

extern "C" void kernel_launch(void* const* d_in, const int* in_sizes, int n_in,
                              void* d_out, int out_size, void* d_ws, size_t ws_size,
                              hipStream_t stream) {
    const float* x    = (const float*)d_in[0];
    const float* Wih0 = (const float*)d_in[1];
    const float* Whh0 = (const float*)d_in[2];
    const float* bih0 = (const float*)d_in[3];
    const float* bhh0 = (const float*)d_in[4];
    const float* Wih1 = (const float*)d_in[5];
    const float* Whh1 = (const float*)d_in[6];
    const float* bih1 = (const float*)d_in[7];
    const float* bhh1 = (const float*)d_in[8];
    const float* Wfc  = (const float*)d_in[9];
    const float* bfc  = (const float*)d_in[10];
    float* out = (float*)d_out;

    hipLaunchKernelGGL(gru_fused, dim3(512 / BT), dim3(NTHR), 0, stream,
                       x, Wih0, Whh0, bih0, bhh0, Wih1, Whh1, bih1, bhh1, Wfc, bfc, out);
}